// Round 1
// baseline (102.365 us; speedup 1.0000x reference)
//
#include <hip/hip_runtime.h>

// Pipeline_8400956031319: dual greedy NMS (8192 det + 8192 rpn, IOU>0.6,
// index order) + argmax masking.
//
// R12 rev — attack address-divergence, not latency. R6-R10 scanpair pinned
// at 43-46us for wildly different work and R11's 8-deep MLP batching didn't
// move the total => the scan is TA/L1 *throughput*-bound: scalar dword
// loads at lane-stride 36B/24B touch ~24-36 cache lines per wave-load inst
// (~1 line/cyc L1 tag rate => ~30K cyc/CU just in address processing).
// Fix: stage contiguous 1024-row chunks into LDS with coalesced float4
// loads (reg-double-buffered so chunk c+1 HBM/L2 latency hides under the
// chunk-c scan), then scan from LDS (dword stride 9 is coprime with 32
// banks => 2-way alias = free). Same treatment for solve_epi's epilogue:
// per-row masks to LDS once, then stream the 512-row slice as contiguous
// float4 with exact magic-mul row decode (d/9, d/6).
//
//   K1 scanpair (512 blocks x 512 thr, one block per (cell,set)):
//     8 chunks x 1024 rows: coalesced float4 global->LDS stage, scan 2
//     rows/thread/chunk from LDS; 3x3 neighborhood filter (box <=120 <
//     128px cell => only 3x3 can overlap); flattened pair loop; exact ref
//     IOU; emit edges (i<<13|j, once via orig_a < orig_b) to a private
//     per-block region. No global atomics, no init kernel.
//   K2 solve_epi (32 blocks x 1024): gather set's ~3k edges to LDS,
//     Jacobi fixpoint keep[j] = !(exists i<j edge with keep[i]) (unique
//     fixpoint == greedy NMS), then coalesced float4 epilogue slice.

constexpr int NROWS = 8192;
constexpr int NKW   = 256;      // keep words (u32) per set
constexpr unsigned BCAP = 1536; // staged neighborhood cap (mean ~288)
constexpr unsigned ACAP = 512;  // cell-member cap (mean ~32)
constexpr unsigned RCAP = 2048; // per-block edge region cap (mean ~12)
constexpr unsigned ELDS = 16384;// solve LDS edge cache
#define IOU_T 0.6f

// ws layout: cnts[2][256] u32 @ 0 ; edges[2*256][RCAP] u32 @ 4096
constexpr size_t OFF_EDGES = 4096;

// ---------------------------------------------------------------------------
// K1: fused scan + pair. grid = (256 cells, 2 sets) x 512 threads.
// ---------------------------------------------------------------------------
__global__ __launch_bounds__(512) void scanpair_kernel(
    const float* __restrict__ det, const float* __restrict__ rpn,
    unsigned* __restrict__ cnts, unsigned* __restrict__ edges)
{
  const int cellid = blockIdx.x, set = blockIdx.y;
  const float* src  = (set == 0) ? det : rpn;
  const int    strd = (set == 0) ? 9 : 6;
  unsigned* myedges = edges + ((size_t)(set * 256 + cellid)) * RCAP;
  const int cx = cellid & 15, cy = cellid >> 4;

  __shared__ float Bx1[BCAP], By1[BCAP], Bx2[BCAP], By2[BCAP], Bar[BCAP];
  __shared__ unsigned Bid[BCAP];
  __shared__ unsigned aList[ACAP];
  __shared__ unsigned bCnt, aCnt, eCnt, ovf;
  __shared__ __align__(16) float chunkBuf[9216];  // 1024 rows x strd (<=9) dw

  const int t = threadIdx.x;
  if (t == 0) { bCnt = 0u; aCnt = 0u; eCnt = 0u; ovf = 0u; }

  // chunked coalesced scan: 8 chunks x 1024 rows. Chunk rows are CONTIGUOUS
  // dwords => float4 stage is fully coalesced (16 lines/wave-inst for 256
  // dwords, vs ~36 lines/wave-inst for 64 dwords in the strided scan).
  const int n4 = (1024 * strd) >> 2;              // float4/chunk: 2304 / 1536
  const float4* s4 = reinterpret_cast<const float4*>(src);

  float4 reg[5];                                   // reg double-buffer
  #pragma unroll
  for (int j = 0; j < 5; ++j) {                    // prologue: chunk 0
    const int idx = t + j * 512;
    if (idx < n4) reg[j] = s4[idx];
  }
  #pragma unroll
  for (int j = 0; j < 5; ++j) {
    const int idx = t + j * 512;
    if (idx < n4) *reinterpret_cast<float4*>(&chunkBuf[idx << 2]) = reg[j];
  }
  __syncthreads();                                 // covers counters + chunk 0

  for (int c = 0; c < 8; ++c) {
    if (c < 7) {                                   // issue chunk c+1 early:
      #pragma unroll                               // latency hides under scan
      for (int j = 0; j < 5; ++j) {
        const int idx = t + j * 512;
        if (idx < n4) reg[j] = s4[(c + 1) * n4 + idx];
      }
    }
    // consume chunk c from LDS: stride-9 dwords => 2-way bank alias (free)
    #pragma unroll
    for (int k = 0; k < 2; ++k) {
      const int rl = t + k * 512;                  // row within chunk
      const int r  = c * 1024 + rl;                // global row
      const float* b = &chunkBuf[rl * strd + 1];
      const float x1 = b[0], y1 = b[1], x2 = b[2], y2 = b[3];
      const float cxe = 0.5f * (x1 + x2), cye = 0.5f * (y1 + y2);
      const int ccx = min(15, max(0, (int)(cxe * (1.0f / 128.0f))));
      const int ccy = min(15, max(0, (int)(cye * (1.0f / 128.0f))));
      const int dx = ccx - cx, dy = ccy - cy;
      if (dx >= -1 && dx <= 1 && dy >= -1 && dy <= 1) {
        const unsigned s = atomicAdd(&bCnt, 1u);
        if (s < BCAP) {
          Bx1[s] = x1; By1[s] = y1; Bx2[s] = x2; By2[s] = y2;
          Bar[s] = fmaxf(x2 - x1, 0.0f) * fmaxf(y2 - y1, 0.0f); // ref area
          Bid[s] = (unsigned)r;
          if (dx == 0 && dy == 0) {
            const unsigned as = atomicAdd(&aCnt, 1u);
            if (as < ACAP) aList[as] = s; else atomicOr(&ovf, 1u);
          }
        } else atomicOr(&ovf, 1u);
      }
    }
    __syncthreads();                               // chunk c fully consumed
    if (c < 7) {
      #pragma unroll
      for (int j = 0; j < 5; ++j) {
        const int idx = t + j * 512;
        if (idx < n4) *reinterpret_cast<float4*>(&chunkBuf[idx << 2]) = reg[j];
      }
      __syncthreads();                             // chunk c+1 visible
    }
  }
  __syncthreads();

  const unsigned nb = min(bCnt, BCAP);
  const unsigned na = min(aCnt, ACAP);

  if (!ovf) {
    // flattened pair phase: all tests independent, LDS-resident
    const unsigned tot = na * nb;
    for (unsigned p = t; p < tot; p += 512) {
      const unsigned ai = p / nb, x = p - ai * nb;
      const unsigned s = aList[ai];
      const unsigned ia = Bid[s], ib = Bid[x];
      if (ia < ib) {                                   // emit-once; skips self
        const float ix1 = fmaxf(Bx1[s], Bx1[x]), iy1 = fmaxf(By1[s], By1[x]);
        const float ix2 = fminf(Bx2[s], Bx2[x]), iy2 = fminf(By2[s], By2[x]);
        const float inter = fmaxf(ix2 - ix1, 0.0f) * fmaxf(iy2 - iy1, 0.0f);
        if (inter > 0.0f) {
          const float uni = Bar[s] + Bar[x] - inter;          // ref order
          const float iou = inter / fmaxf(uni, 1e-9f);        // ref expr
          if (iou > IOU_T) {
            const unsigned slot = atomicAdd(&eCnt, 1u);       // LDS atomic
            if (slot < RCAP) myedges[slot] = (ia << 13) | ib;
          }
        }
      }
    }
  } else {
    // exact fallback (never taken for this data): a = rows in this cell,
    // b = ALL rows; out-of-neighborhood pairs have inter==0 geometrically,
    // so semantics are identical to the fast path.
    for (int ra = 0; ra < NROWS; ++ra) {
      const float* pa = src + (size_t)ra * strd + 1;
      const float ax1 = pa[0], ay1 = pa[1], ax2 = pa[2], ay2 = pa[3];
      const float cxe = 0.5f * (ax1 + ax2), cye = 0.5f * (ay1 + ay2);
      const int ccx = min(15, max(0, (int)(cxe * (1.0f / 128.0f))));
      const int ccy = min(15, max(0, (int)(cye * (1.0f / 128.0f))));
      if (ccx != cx || ccy != cy) continue;            // uniform skip
      const float aar = fmaxf(ax2 - ax1, 0.0f) * fmaxf(ay2 - ay1, 0.0f);
      for (int rb = t; rb < NROWS; rb += 512) {
        if ((unsigned)ra >= (unsigned)rb) continue;
        const float* pb = src + (size_t)rb * strd + 1;
        const float bx1 = pb[0], by1 = pb[1], bx2 = pb[2], by2 = pb[3];
        const float ix1 = fmaxf(ax1, bx1), iy1 = fmaxf(ay1, by1);
        const float ix2 = fminf(ax2, bx2), iy2 = fminf(ay2, by2);
        const float inter = fmaxf(ix2 - ix1, 0.0f) * fmaxf(iy2 - iy1, 0.0f);
        if (inter > 0.0f) {
          const float bar = fmaxf(bx2 - bx1, 0.0f) * fmaxf(by2 - by1, 0.0f);
          const float uni = aar + bar - inter;
          const float iou = inter / fmaxf(uni, 1e-9f);
          if (iou > IOU_T) {
            const unsigned slot = atomicAdd(&eCnt, 1u);
            if (slot < RCAP) myedges[slot] = ((unsigned)ra << 13) | (unsigned)rb;
          }
        }
      }
    }
  }
  __syncthreads();
  if (t == 0) cnts[set * 256 + cellid] = min(eCnt, RCAP);
}

// ---------------------------------------------------------------------------
// K2: fixpoint + epilogue. grid = 32 blocks x 1024. set = blk>>4; each block
// solves its set's fixpoint (redundantly, ~3k edges) then writes rows
// [slice*512, slice*512+512) of its outputs via coalesced float4 streaming.
// ---------------------------------------------------------------------------
__global__ __launch_bounds__(1024) void solve_epi_kernel(
    const float* __restrict__ det, const float* __restrict__ rpn,
    const unsigned* __restrict__ cnts, const unsigned* __restrict__ edges,
    float* __restrict__ out)
{
  const int blk = blockIdx.x;
  const int set = blk >> 4;
  const int slice = blk & 15;
  const unsigned* gedges = edges + (size_t)set * 256 * RCAP;

  __shared__ unsigned eL[ELDS];
  __shared__ unsigned rcnt[256], roff[256];
  __shared__ unsigned kbuf[2][NKW];
  __shared__ int changed[2];
  __shared__ unsigned Etot_sh;
  __shared__ float vmsk[512], imsk[512];   // per-row epilogue masks

  const int t = threadIdx.x;
  if (t < 256) rcnt[t] = min(cnts[set * 256 + t], RCAP);
  __syncthreads();

  // wave0 shuffle-scan of 256 region counts (4/lane)
  if (t < 64) {
    const unsigned h0 = rcnt[4 * t], h1 = rcnt[4 * t + 1];
    const unsigned h2 = rcnt[4 * t + 2], h3 = rcnt[4 * t + 3];
    const unsigned lsum = h0 + h1 + h2 + h3;
    unsigned incl = lsum;
    #pragma unroll
    for (int d = 1; d < 64; d <<= 1) {
      const unsigned v = __shfl_up(incl, d);
      if (t >= d) incl += v;
    }
    const unsigned base = incl - lsum;
    roff[4 * t] = base;               roff[4 * t + 1] = base + h0;
    roff[4 * t + 2] = base + h0 + h1; roff[4 * t + 3] = base + h0 + h1 + h2;
    if (t == 63) Etot_sh = incl;
  }
  if (t < NKW) kbuf[0][t] = 0xFFFFFFFFu;
  __syncthreads();

  const unsigned Etot = Etot_sh;
  const bool cached = (Etot <= ELDS);
  if (cached) {                 // gather: 4 threads per region (~3 loads ea)
    const unsigned rg = (unsigned)t >> 2, ln = (unsigned)t & 3u;
    const unsigned c = rcnt[rg], o = roff[rg];
    for (unsigned k = ln; k < c; k += 4u)
      eL[o + k] = gedges[(size_t)rg * RCAP + k];
  }
  __syncthreads();

  int cur = 0;
  for (int round = 0; round < NROWS + 8; ++round) {
    const int nxt = cur ^ 1;
    if (t == 0) changed[round & 1] = 0;
    if (t < NKW) kbuf[nxt][t] = 0xFFFFFFFFu;
    __syncthreads();

    if (cached) {
      for (unsigned e = t; e < Etot; e += 1024) {
        const unsigned pk = eL[e];
        const unsigned i = pk >> 13, j = pk & 8191u;
        if ((kbuf[cur][i >> 5] >> (i & 31)) & 1u)
          atomicAnd(&kbuf[nxt][j >> 5], ~(1u << (j & 31)));
      }
    } else {                    // exact slow path (never taken)
      for (unsigned r = (unsigned)t >> 2; r < 256u; r += 256u) {
        const unsigned c = rcnt[r];
        for (unsigned k = (unsigned)t & 3u; k < c; k += 4u) {
          const unsigned pk = gedges[(size_t)r * RCAP + k];
          const unsigned i = pk >> 13, j = pk & 8191u;
          if ((kbuf[cur][i >> 5] >> (i & 31)) & 1u)
            atomicAnd(&kbuf[nxt][j >> 5], ~(1u << (j & 31)));
        }
      }
    }
    __syncthreads();

    if (t < NKW && kbuf[nxt][t] != kbuf[cur][t]) changed[round & 1] = 1;
    __syncthreads();

    cur = nxt;
    if (!changed[round & 1]) break;  // F(x)==x -> the unique fixpoint
  }

  // epilogue slice: 512 rows per block, coalesced.
  // phase 1: per-row mask (0.0/1.0) into LDS; phase 2: stream contiguous
  // float4 with exact magic-div row decode (col stride 9 => d/9, 6 => d/6).
  const int r0 = slice * 512;
  if (set == 0) {
    if (t < 512) {
      const int i = r0 + t;
      const bool kd = (kbuf[cur][i >> 5] >> (i & 31)) & 1u;
      const float* p = det + (size_t)i * 9;
      const float sc0 = p[5], sc1 = p[6], sc2 = p[7], sc3 = p[8];
      int am = 0; float best = sc0;
      if (sc1 > best) { best = sc1; am = 1; }   // first-max, like jnp.argmax
      if (sc2 > best) { best = sc2; am = 2; }
      if (sc3 > best) { best = sc3; am = 3; }
      vmsk[t] = (kd && am != 0) ? 1.0f : 0.0f;
      imsk[t] = (kd && am == 0) ? 1.0f : 0.0f;
    }
    __syncthreads();
    // slice = 512 rows x 9 dw = 4608 dw = 1152 float4, 16B-aligned bases
    const float4* in4 = reinterpret_cast<const float4*>(det + (size_t)r0 * 9);
    float4* o0 = reinterpret_cast<float4*>(out + (size_t)r0 * 9);
    float4* o1 = reinterpret_cast<float4*>(out + (size_t)NROWS * 9 + (size_t)r0 * 9);
    for (int q = t; q < 1152; q += 1024) {
      const float4 v = in4[q];
      const float* vp = reinterpret_cast<const float*>(&v);
      float4 a, b;
      float* ap = reinterpret_cast<float*>(&a);
      float* bp = reinterpret_cast<float*>(&b);
      #pragma unroll
      for (int j = 0; j < 4; ++j) {
        const unsigned d = (unsigned)(q * 4 + j);
        const unsigned row = (d * 7282u) >> 16;        // == d/9 for d<4608
        ap[j] = vp[j] * vmsk[row];
        bp[j] = vp[j] * imsk[row];
      }
      o0[q] = a; o1[q] = b;
    }
  } else {
    if (t < 512) {
      const int i = r0 + t;
      const bool kr = (kbuf[cur][i >> 5] >> (i & 31)) & 1u;
      vmsk[t] = kr ? 1.0f : 0.0f;
    }
    __syncthreads();
    // slice = 512 rows x 6 dw = 3072 dw = 768 float4, 16B-aligned bases
    const float4* in4 = reinterpret_cast<const float4*>(rpn + (size_t)r0 * 6);
    float4* o2 = reinterpret_cast<float4*>(out + (size_t)NROWS * 18 + (size_t)r0 * 6);
    for (int q = t; q < 768; q += 1024) {
      const float4 v = in4[q];
      const float* vp = reinterpret_cast<const float*>(&v);
      float4 a;
      float* ap = reinterpret_cast<float*>(&a);
      #pragma unroll
      for (int j = 0; j < 4; ++j) {
        const unsigned d = (unsigned)(q * 4 + j);
        const unsigned row = (d * 10923u) >> 16;       // == d/6 for d<3072
        ap[j] = vp[j] * vmsk[row];
      }
      o2[q] = a;
    }
  }
}

// ---------------------------------------------------------------------------
extern "C" void kernel_launch(void* const* d_in, const int* in_sizes, int n_in,
                              void* d_out, int out_size, void* d_ws, size_t ws_size,
                              hipStream_t stream)
{
  const float* det = (const float*)d_in[0];   // 8192 x 9 fp32
  const float* rpn = (const float*)d_in[1];   // 8192 x 6 fp32
  float* out = (float*)d_out;                 // 8192*9 + 8192*9 + 8192*6 fp32

  char* ws = (char*)d_ws;
  unsigned* cnts  = (unsigned*)ws;            // [2][256] u32
  unsigned* edges = (unsigned*)(ws + OFF_EDGES);

  dim3 g1(256, 2);
  scanpair_kernel<<<g1, 512, 0, stream>>>(det, rpn, cnts, edges);
  solve_epi_kernel<<<32, 1024, 0, stream>>>(det, rpn, cnts, edges, out);
}

// Round 2
// 79.495 us; speedup vs baseline: 1.2877x; 1.2877x over previous
//
#include <hip/hip_runtime.h>

// Pipeline_8400956031319: dual greedy NMS (8192 det + 8192 rpn, IOU>0.6,
// index order) + argmax masking.
//
// R13 rev — kill the 512x redundant scan. R6-R11 strided full-scan cost
// ~15-22us (address divergence: 36B-stride scalar loads touch ~36 lines
// per wave-load inst); R12's LDS-staged scan regressed to 49us (barrier-
// serialized chunks @ 2 blocks/CU, VALUBusy 16%, HBM 16% — nothing busy).
// Root cause both times: every (cell,set) block scanned ALL 8192 rows.
// Fix: bin once, gather per-block.
//
//   D1 hipMemsetAsync: zero bin counters + ovf flag (2.1 KB).
//   D2 bin_kernel (32 blocks x 512): ONE pass over 16K rows; compute cell
//      (identical clamp formula), scatter {box float4, row id} into
//      per-(set,cell) bins via global atomicAdd slots. ~2us.
//   D3 pair_kernel (256 cells, 2 sets) x 512: gather 3x3 neighborhood
//      (~288 entries; per-cell runs are contiguous float4 => coalesced)
//      into LDS, center cell first (a-range = [0,na)); identical flattened
//      pair loop + exact ref IOU; emit edges (i<<13|j) once via
//      orig_a < orig_b (exactly one center-block wins per pair; dupes
//      would be idempotent under solve's atomicAnd anyway). Overflow of
//      any bin (>ACAP) or neighborhood (>BCAP) => exact full-scan
//      fallback (never taken for this data).
//   D4 solve_epi (32 blocks x 1024): unchanged known-good — LDS edge
//      cache, Jacobi fixpoint keep[j] = !(exists i<j edge with keep[i])
//      (unique fixpoint == greedy NMS), coalesced float4 epilogue.

constexpr int NROWS = 8192;
constexpr int NKW   = 256;      // keep words (u32) per set
constexpr unsigned ACAP = 512;  // bin capacity per (set,cell) (mean ~32)
constexpr unsigned BCAP = 1536; // staged 3x3 neighborhood cap (mean ~288)
constexpr unsigned RCAP = 2048; // per-block edge region cap (mean ~12)
constexpr unsigned ELDS = 16384;// solve LDS edge cache
#define IOU_T 0.6f

// ws layout:
//   [0      ) edge cnts  [512] u32   (written unconditionally by pair)
//   [2048   ) bin  cnts  [512] u32   (memset-zeroed)
//   [4096   ) ovf flag   u32         (memset-zeroed)
//   [8192   ) edges      [512][RCAP] u32   (4 MB)
//   [+4MB   ) binBox     [512][ACAP] float4 (4 MB, 16B-aligned)
//   [+4MB   ) binId      [512][ACAP] u32    (1 MB)
constexpr size_t OFF_ECNT  = 0;
constexpr size_t OFF_BCNT  = 2048;
constexpr size_t OFF_OVF   = 4096;
constexpr size_t OFF_EDGES = 8192;
constexpr size_t OFF_BBOX  = OFF_EDGES + (size_t)512 * RCAP * 4;
constexpr size_t OFF_BID   = OFF_BBOX  + (size_t)512 * ACAP * 16;

// ---------------------------------------------------------------------------
// D2: bin. 32 blocks x 512 threads = 16384 rows (8192 x 2 sets).
// ---------------------------------------------------------------------------
__global__ __launch_bounds__(512) void bin_kernel(
    const float* __restrict__ det, const float* __restrict__ rpn,
    unsigned* __restrict__ binCnt, float4* __restrict__ binBox,
    unsigned* __restrict__ binId, unsigned* __restrict__ ovf)
{
  const int b = blockIdx.x;
  const int set = b >> 4;
  const int r = ((b & 15) << 9) + threadIdx.x;
  const float* src  = (set == 0) ? det : rpn;
  const int    strd = (set == 0) ? 9 : 6;

  const float* p = src + (size_t)r * strd + 1;
  const float x1 = p[0], y1 = p[1], x2 = p[2], y2 = p[3];
  const float cxe = 0.5f * (x1 + x2), cye = 0.5f * (y1 + y2);
  const int ccx = min(15, max(0, (int)(cxe * (1.0f / 128.0f))));
  const int ccy = min(15, max(0, (int)(cye * (1.0f / 128.0f))));
  const unsigned cell = (unsigned)(set * 256 + ccy * 16 + ccx);

  const unsigned slot = atomicAdd(&binCnt[cell], 1u);
  if (slot < ACAP) {
    binBox[(size_t)cell * ACAP + slot] = make_float4(x1, y1, x2, y2);
    binId [(size_t)cell * ACAP + slot] = (unsigned)r;
  } else {
    atomicOr(ovf, 1u);
  }
}

// ---------------------------------------------------------------------------
// D3: pair. grid = (256 cells, 2 sets) x 512 threads.
// ---------------------------------------------------------------------------
__global__ __launch_bounds__(512) void pair_kernel(
    const float* __restrict__ det, const float* __restrict__ rpn,
    const unsigned* __restrict__ binCnt, const float4* __restrict__ binBox,
    const unsigned* __restrict__ binId, const unsigned* __restrict__ ovfp,
    unsigned* __restrict__ cnts, unsigned* __restrict__ edges)
{
  const int cellid = blockIdx.x, set = blockIdx.y;
  const int cx = cellid & 15, cy = cellid >> 4;
  unsigned* myedges = edges + ((size_t)(set * 256 + cellid)) * RCAP;

  __shared__ float4 B4[BCAP];
  __shared__ float  Bar[BCAP];
  __shared__ unsigned Bid[BCAP];
  __shared__ unsigned ncell[9], ncnt[9], noff[9];
  __shared__ unsigned nN_sh, na_sh, nb_sh, eCnt, bad;

  const int t = threadIdx.x;
  if (t == 0) {
    unsigned nN = 0;
    ncell[nN++] = (unsigned)(set * 256 + cellid);   // CENTER FIRST
    for (int dy = -1; dy <= 1; ++dy)
      for (int dx = -1; dx <= 1; ++dx) {
        if (dx == 0 && dy == 0) continue;
        const int nx = cx + dx, ny = cy + dy;
        if (nx >= 0 && nx < 16 && ny >= 0 && ny < 16)
          ncell[nN++] = (unsigned)(set * 256 + ny * 16 + nx);
      }
    nN_sh = nN; eCnt = 0u; bad = *ovfp;
  }
  __syncthreads();
  const unsigned nN = nN_sh;
  if (t < (int)nN) ncnt[t] = min(binCnt[ncell[t]], ACAP);
  __syncthreads();
  if (t == 0) {
    unsigned off = 0;
    for (unsigned n = 0; n < nN; ++n) { noff[n] = off; off += ncnt[n]; }
    na_sh = ncnt[0]; nb_sh = off;
    if (off > BCAP) bad = 1u;
  }
  __syncthreads();

  const unsigned na = na_sh, nb = nb_sh;
  const bool ok = (bad == 0u);

  if (ok) {
    // gather neighborhood: per-cell contiguous float4 runs => coalesced
    for (unsigned idx = t; idx < nb; idx += 512) {
      unsigned n = 0;
      while (idx >= noff[n] + ncnt[n]) ++n;          // <=9 iterations
      const unsigned k = idx - noff[n];
      const size_t  g = (size_t)ncell[n] * ACAP + k;
      const float4 bx = binBox[g];
      B4[idx]  = bx;
      Bar[idx] = fmaxf(bx.z - bx.x, 0.0f) * fmaxf(bx.w - bx.y, 0.0f); // ref
      Bid[idx] = binId[g];
    }
  }
  __syncthreads();

  if (ok) {
    // flattened pair phase: a = center entries [0,na), b = all [0,nb)
    const unsigned tot = na * nb;
    for (unsigned p = t; p < tot; p += 512) {
      const unsigned ai = p / nb, x = p - ai * nb;
      const unsigned ia = Bid[ai], ib = Bid[x];
      if (ia < ib) {                                 // emit-once; skips self
        const float4 A = B4[ai], B = B4[x];
        const float ix1 = fmaxf(A.x, B.x), iy1 = fmaxf(A.y, B.y);
        const float ix2 = fminf(A.z, B.z), iy2 = fminf(A.w, B.w);
        const float inter = fmaxf(ix2 - ix1, 0.0f) * fmaxf(iy2 - iy1, 0.0f);
        if (inter > 0.0f) {
          const float uni = Bar[ai] + Bar[x] - inter;       // ref order
          const float iou = inter / fmaxf(uni, 1e-9f);      // ref expr
          if (iou > IOU_T) {
            const unsigned slot = atomicAdd(&eCnt, 1u);     // LDS atomic
            if (slot < RCAP) myedges[slot] = (ia << 13) | ib;
          }
        }
      }
    }
  } else {
    // exact fallback (never taken for this data): a = rows in this cell,
    // b = ALL rows; out-of-neighborhood pairs have inter==0 geometrically,
    // so semantics are identical to the fast path.
    const float* src  = (set == 0) ? det : rpn;
    const int    strd = (set == 0) ? 9 : 6;
    for (int ra = 0; ra < NROWS; ++ra) {
      const float* pa = src + (size_t)ra * strd + 1;
      const float ax1 = pa[0], ay1 = pa[1], ax2 = pa[2], ay2 = pa[3];
      const float cxe = 0.5f * (ax1 + ax2), cye = 0.5f * (ay1 + ay2);
      const int ccx = min(15, max(0, (int)(cxe * (1.0f / 128.0f))));
      const int ccy = min(15, max(0, (int)(cye * (1.0f / 128.0f))));
      if (ccx != cx || ccy != cy) continue;          // uniform skip
      const float aar = fmaxf(ax2 - ax1, 0.0f) * fmaxf(ay2 - ay1, 0.0f);
      for (int rb = t; rb < NROWS; rb += 512) {
        if ((unsigned)ra >= (unsigned)rb) continue;
        const float* pb = src + (size_t)rb * strd + 1;
        const float bx1 = pb[0], by1 = pb[1], bx2 = pb[2], by2 = pb[3];
        const float ix1 = fmaxf(ax1, bx1), iy1 = fmaxf(ay1, by1);
        const float ix2 = fminf(ax2, bx2), iy2 = fminf(ay2, by2);
        const float inter = fmaxf(ix2 - ix1, 0.0f) * fmaxf(iy2 - iy1, 0.0f);
        if (inter > 0.0f) {
          const float bar = fmaxf(bx2 - bx1, 0.0f) * fmaxf(by2 - by1, 0.0f);
          const float uni = aar + bar - inter;
          const float iou = inter / fmaxf(uni, 1e-9f);
          if (iou > IOU_T) {
            const unsigned slot = atomicAdd(&eCnt, 1u);
            if (slot < RCAP) myedges[slot] = ((unsigned)ra << 13) | (unsigned)rb;
          }
        }
      }
    }
  }
  __syncthreads();
  if (t == 0) cnts[set * 256 + cellid] = min(eCnt, RCAP);
}

// ---------------------------------------------------------------------------
// D4: fixpoint + epilogue. grid = 32 blocks x 1024. set = blk>>4; each block
// solves its set's fixpoint (redundantly, ~3k edges) then writes rows
// [slice*512, slice*512+512) of its outputs via coalesced float4 streaming.
// ---------------------------------------------------------------------------
__global__ __launch_bounds__(1024) void solve_epi_kernel(
    const float* __restrict__ det, const float* __restrict__ rpn,
    const unsigned* __restrict__ cnts, const unsigned* __restrict__ edges,
    float* __restrict__ out)
{
  const int blk = blockIdx.x;
  const int set = blk >> 4;
  const int slice = blk & 15;
  const unsigned* gedges = edges + (size_t)set * 256 * RCAP;

  __shared__ unsigned eL[ELDS];
  __shared__ unsigned rcnt[256], roff[256];
  __shared__ unsigned kbuf[2][NKW];
  __shared__ int changed[2];
  __shared__ unsigned Etot_sh;
  __shared__ float vmsk[512], imsk[512];   // per-row epilogue masks

  const int t = threadIdx.x;
  if (t < 256) rcnt[t] = min(cnts[set * 256 + t], RCAP);
  __syncthreads();

  // wave0 shuffle-scan of 256 region counts (4/lane)
  if (t < 64) {
    const unsigned h0 = rcnt[4 * t], h1 = rcnt[4 * t + 1];
    const unsigned h2 = rcnt[4 * t + 2], h3 = rcnt[4 * t + 3];
    const unsigned lsum = h0 + h1 + h2 + h3;
    unsigned incl = lsum;
    #pragma unroll
    for (int d = 1; d < 64; d <<= 1) {
      const unsigned v = __shfl_up(incl, d);
      if (t >= d) incl += v;
    }
    const unsigned base = incl - lsum;
    roff[4 * t] = base;               roff[4 * t + 1] = base + h0;
    roff[4 * t + 2] = base + h0 + h1; roff[4 * t + 3] = base + h0 + h1 + h2;
    if (t == 63) Etot_sh = incl;
  }
  if (t < NKW) kbuf[0][t] = 0xFFFFFFFFu;
  __syncthreads();

  const unsigned Etot = Etot_sh;
  const bool cached = (Etot <= ELDS);
  if (cached) {                 // gather: 4 threads per region (~3 loads ea)
    const unsigned rg = (unsigned)t >> 2, ln = (unsigned)t & 3u;
    const unsigned c = rcnt[rg], o = roff[rg];
    for (unsigned k = ln; k < c; k += 4u)
      eL[o + k] = gedges[(size_t)rg * RCAP + k];
  }
  __syncthreads();

  int cur = 0;
  for (int round = 0; round < NROWS + 8; ++round) {
    const int nxt = cur ^ 1;
    if (t == 0) changed[round & 1] = 0;
    if (t < NKW) kbuf[nxt][t] = 0xFFFFFFFFu;
    __syncthreads();

    if (cached) {
      for (unsigned e = t; e < Etot; e += 1024) {
        const unsigned pk = eL[e];
        const unsigned i = pk >> 13, j = pk & 8191u;
        if ((kbuf[cur][i >> 5] >> (i & 31)) & 1u)
          atomicAnd(&kbuf[nxt][j >> 5], ~(1u << (j & 31)));
      }
    } else {                    // exact slow path (never taken)
      for (unsigned r = (unsigned)t >> 2; r < 256u; r += 256u) {
        const unsigned c = rcnt[r];
        for (unsigned k = (unsigned)t & 3u; k < c; k += 4u) {
          const unsigned pk = gedges[(size_t)r * RCAP + k];
          const unsigned i = pk >> 13, j = pk & 8191u;
          if ((kbuf[cur][i >> 5] >> (i & 31)) & 1u)
            atomicAnd(&kbuf[nxt][j >> 5], ~(1u << (j & 31)));
        }
      }
    }
    __syncthreads();

    if (t < NKW && kbuf[nxt][t] != kbuf[cur][t]) changed[round & 1] = 1;
    __syncthreads();

    cur = nxt;
    if (!changed[round & 1]) break;  // F(x)==x -> the unique fixpoint
  }

  // epilogue slice: 512 rows per block, coalesced.
  // phase 1: per-row mask (0.0/1.0) into LDS; phase 2: stream contiguous
  // float4 with exact magic-div row decode (col stride 9 => d/9, 6 => d/6).
  const int r0 = slice * 512;
  if (set == 0) {
    if (t < 512) {
      const int i = r0 + t;
      const bool kd = (kbuf[cur][i >> 5] >> (i & 31)) & 1u;
      const float* p = det + (size_t)i * 9;
      const float sc0 = p[5], sc1 = p[6], sc2 = p[7], sc3 = p[8];
      int am = 0; float best = sc0;
      if (sc1 > best) { best = sc1; am = 1; }   // first-max, like jnp.argmax
      if (sc2 > best) { best = sc2; am = 2; }
      if (sc3 > best) { best = sc3; am = 3; }
      vmsk[t] = (kd && am != 0) ? 1.0f : 0.0f;
      imsk[t] = (kd && am == 0) ? 1.0f : 0.0f;
    }
    __syncthreads();
    // slice = 512 rows x 9 dw = 4608 dw = 1152 float4, 16B-aligned bases
    const float4* in4 = reinterpret_cast<const float4*>(det + (size_t)r0 * 9);
    float4* o0 = reinterpret_cast<float4*>(out + (size_t)r0 * 9);
    float4* o1 = reinterpret_cast<float4*>(out + (size_t)NROWS * 9 + (size_t)r0 * 9);
    for (int q = t; q < 1152; q += 1024) {
      const float4 v = in4[q];
      const float* vp = reinterpret_cast<const float*>(&v);
      float4 a, b;
      float* ap = reinterpret_cast<float*>(&a);
      float* bp = reinterpret_cast<float*>(&b);
      #pragma unroll
      for (int j = 0; j < 4; ++j) {
        const unsigned d = (unsigned)(q * 4 + j);
        const unsigned row = (d * 7282u) >> 16;        // == d/9 for d<4608
        ap[j] = vp[j] * vmsk[row];
        bp[j] = vp[j] * imsk[row];
      }
      o0[q] = a; o1[q] = b;
    }
  } else {
    if (t < 512) {
      const int i = r0 + t;
      const bool kr = (kbuf[cur][i >> 5] >> (i & 31)) & 1u;
      vmsk[t] = kr ? 1.0f : 0.0f;
    }
    __syncthreads();
    // slice = 512 rows x 6 dw = 3072 dw = 768 float4, 16B-aligned bases
    const float4* in4 = reinterpret_cast<const float4*>(rpn + (size_t)r0 * 6);
    float4* o2 = reinterpret_cast<float4*>(out + (size_t)NROWS * 18 + (size_t)r0 * 6);
    for (int q = t; q < 768; q += 1024) {
      const float4 v = in4[q];
      const float* vp = reinterpret_cast<const float*>(&v);
      float4 a;
      float* ap = reinterpret_cast<float*>(&a);
      #pragma unroll
      for (int j = 0; j < 4; ++j) {
        const unsigned d = (unsigned)(q * 4 + j);
        const unsigned row = (d * 10923u) >> 16;       // == d/6 for d<3072
        ap[j] = vp[j] * vmsk[row];
      }
      o2[q] = a;
    }
  }
}

// ---------------------------------------------------------------------------
extern "C" void kernel_launch(void* const* d_in, const int* in_sizes, int n_in,
                              void* d_out, int out_size, void* d_ws, size_t ws_size,
                              hipStream_t stream)
{
  const float* det = (const float*)d_in[0];   // 8192 x 9 fp32
  const float* rpn = (const float*)d_in[1];   // 8192 x 6 fp32
  float* out = (float*)d_out;                 // 8192*9 + 8192*9 + 8192*6 fp32

  char* ws = (char*)d_ws;
  unsigned* ecnt   = (unsigned*)(ws + OFF_ECNT);
  unsigned* binCnt = (unsigned*)(ws + OFF_BCNT);
  unsigned* ovf    = (unsigned*)(ws + OFF_OVF);
  unsigned* edges  = (unsigned*)(ws + OFF_EDGES);
  float4*   binBox = (float4*)  (ws + OFF_BBOX);
  unsigned* binId  = (unsigned*)(ws + OFF_BID);

  hipMemsetAsync(ws + OFF_BCNT, 0, 2048 + 64, stream);  // binCnt + ovf

  bin_kernel<<<32, 512, 0, stream>>>(det, rpn, binCnt, binBox, binId, ovf);

  dim3 g1(256, 2);
  pair_kernel<<<g1, 512, 0, stream>>>(det, rpn, binCnt, binBox, binId, ovf,
                                      ecnt, edges);

  solve_epi_kernel<<<32, 1024, 0, stream>>>(det, rpn, ecnt, edges, out);
}